// Round 1
// baseline (3039.512 us; speedup 1.0000x reference)
//
#include <hip/hip_runtime.h>
#include <math.h>

#define NN 50000
#define NF 63
#define NE 800000
#define NL 10000
#define NB 4
#define NLAY 5
#define CD 64
#define BN (NB*NN)          // 200000 rows
#define NTILES (BN/CD)      // 3125
#define PAD 65
#define SCAN_NBLK ((NN+255)/256)   // 196

__device__ __forceinline__ float sigm(float v){ return 1.f/(1.f + expf(-v)); }

// ---------------- CSR build ----------------
__global__ void k_hist(const int* __restrict__ edges, int* __restrict__ cnt){
    int e = blockIdx.x*256 + threadIdx.x;
    if (e < NE) atomicAdd(&cnt[edges[NE + e]], 1);
}

__global__ void k_scan1(const int* __restrict__ cnt, int* __restrict__ tmp, int* __restrict__ bsum){
    __shared__ int sh[256];
    int tx = threadIdx.x, i = blockIdx.x*256 + tx;
    int v = (i < NN) ? cnt[i] : 0;
    sh[tx] = v; __syncthreads();
    for (int off = 1; off < 256; off <<= 1){
        int u = (tx >= off) ? sh[tx-off] : 0;
        __syncthreads();
        sh[tx] += u;
        __syncthreads();
    }
    int incl = sh[tx];
    if (i < NN) tmp[i] = incl - v;          // exclusive within block
    if (tx == 255) bsum[blockIdx.x] = incl; // block total
}

__global__ void k_scan2(const int* __restrict__ bsum, int* __restrict__ boff){
    __shared__ int sh[256];
    int tx = threadIdx.x;
    int v = (tx < SCAN_NBLK) ? bsum[tx] : 0;
    sh[tx] = v; __syncthreads();
    for (int off = 1; off < 256; off <<= 1){
        int u = (tx >= off) ? sh[tx-off] : 0;
        __syncthreads();
        sh[tx] += u;
        __syncthreads();
    }
    boff[tx] = sh[tx] - v;                  // exclusive
}

__global__ void k_scan3(const int* __restrict__ tmp, const int* __restrict__ boff,
                        int* __restrict__ row_start, int* __restrict__ cursor){
    int i = blockIdx.x*256 + threadIdx.x;
    if (i < NN){
        int rs = tmp[i] + boff[blockIdx.x];
        row_start[i] = rs;
        cursor[i] = rs;
    }
    if (i == 0) row_start[NN] = NE;
}

__global__ void k_fillcsr(const int* __restrict__ edges, int* __restrict__ cursor, int* __restrict__ csr_src){
    int e = blockIdx.x*256 + threadIdx.x;
    if (e < NE){
        int d = edges[NE + e];
        int pos = atomicAdd(&cursor[d], 1);
        csr_src[pos] = edges[e];
    }
}

// ---------------- x0 build ----------------
__global__ void k_x0(const float* __restrict__ nodes, float* __restrict__ x0){
    int f = blockIdx.x*256 + threadIdx.x;       // float4 index, BN*16 total
    int row = f >> 4, c4 = f & 15;
    int n = row % NN;
    float v[4];
    #pragma unroll
    for (int i = 0; i < 4; ++i){
        int c = c4*4 + i;
        v[i] = (c < NF) ? nodes[(size_t)n*NF + c] : 0.f;
    }
    ((float4*)x0)[f] = make_float4(v[0], v[1], v[2], v[3]);
}

__global__ void k_cov(const float* __restrict__ cov, const int* __restrict__ c2l, float* __restrict__ x0){
    int i = blockIdx.x*256 + threadIdx.x;
    if (i < NB*NL){
        int b = i / NL, j = i % NL;
        int nd = c2l[j];
        x0[((size_t)b*NN + nd)*CD + 63] = cov[i];
    }
}

// ---------------- tile staging ----------------
__device__ __forceinline__ void stage64(const float* __restrict__ g, int nvalid, float* lds, int tx){
    const float4* g4 = (const float4*)g;
    #pragma unroll
    for (int it = 0; it < 4; ++it){
        int f = it*256 + tx;
        int row = f >> 4, c4 = f & 15;
        float4 v = make_float4(0.f,0.f,0.f,0.f);
        if (row < nvalid) v = g4[f];
        int base = row*PAD + c4*4;
        lds[base+0] = v.x; lds[base+1] = v.y; lds[base+2] = v.z; lds[base+3] = v.w;
    }
}

// ---------------- m = x @ W (64x64), first layer ----------------
__global__ __launch_bounds__(256) void k_mm64(const float* __restrict__ xin, const float* __restrict__ W,
                                              float* __restrict__ mout){
    __shared__ float sx[64*PAD];
    int tx = threadIdx.x, lane = tx & 63;
    int c0 = __builtin_amdgcn_readfirstlane((tx >> 6) * 16);
    size_t row0 = (size_t)blockIdx.x * 64;
    stage64(xin + row0*CD, 64, sx, tx);
    __syncthreads();
    float acc[16];
    #pragma unroll
    for (int j = 0; j < 16; ++j) acc[j] = 0.f;
    #pragma unroll 4
    for (int k = 0; k < 64; ++k){
        float xk = sx[lane*PAD + k];
        #pragma unroll
        for (int j = 0; j < 16; ++j) acc[j] = fmaf(W[k*64 + c0 + j], xk, acc[j]);
    }
    __syncthreads();
    #pragma unroll
    for (int j = 0; j < 16; ++j) sx[lane*PAD + c0 + j] = acc[j];
    __syncthreads();
    #pragma unroll
    for (int rr = 0; rr < 16; ++rr){
        int r = c0 + rr;
        mout[(row0 + r)*CD + lane] = sx[r*PAD + lane];
    }
}

// ---------------- agg = gather-sum over in-edges (all 4 batches) ----------------
__global__ __launch_bounds__(256) void k_agg(const float* __restrict__ m, const int* __restrict__ row_start,
                                             const int* __restrict__ csr_src, float* __restrict__ agg){
    int lane = threadIdx.x & 63;
    int d = blockIdx.x*4 + (threadIdx.x >> 6);
    d = __builtin_amdgcn_readfirstlane(d);
    int e0 = row_start[d], e1 = row_start[d+1];
    float a0 = 0.f, a1 = 0.f, a2 = 0.f, a3 = 0.f;
    for (int e = e0; e < e1; ++e){
        int s = csr_src[e];
        a0 += m[((size_t)0*NN + s)*CD + lane];
        a1 += m[((size_t)1*NN + s)*CD + lane];
        a2 += m[((size_t)2*NN + s)*CD + lane];
        a3 += m[((size_t)3*NN + s)*CD + lane];
    }
    agg[((size_t)0*NN + d)*CD + lane] = a0;
    agg[((size_t)1*NN + d)*CD + lane] = a1;
    agg[((size_t)2*NN + d)*CD + lane] = a2;
    agg[((size_t)3*NN + d)*CD + lane] = a3;
}

// ---------------- one dot-product pass: acc[j] += sum_k lds[lane][k] * Wrow[(c0+j)*64+k] ----------------
__device__ __forceinline__ void dotpass(float acc[16], const float* __restrict__ Wrow, int c0,
                                        const float* lds, int lane){
    for (int kc = 0; kc < 4; ++kc){
        float xk[16];
        #pragma unroll
        for (int t = 0; t < 16; ++t) xk[t] = lds[lane*PAD + kc*16 + t];
        #pragma unroll
        for (int j = 0; j < 16; ++j){
            #pragma unroll
            for (int t = 0; t < 16; ++t)
                acc[j] = fmaf(Wrow[(c0 + j)*64 + kc*16 + t], xk[t], acc[j]);
        }
    }
}

// ---------------- fused GRU + (optional) next-layer m = x' @ Wnext ----------------
__global__ __launch_bounds__(256) void k_gru(const float* __restrict__ xin, const float* __restrict__ aggb,
                                             const float* __restrict__ wih, const float* __restrict__ whh,
                                             const float* __restrict__ bih, const float* __restrict__ bhh,
                                             const float* __restrict__ Wn, float* __restrict__ xout,
                                             float* __restrict__ mout, int do_m){
    __shared__ float sx[64*PAD];
    __shared__ float sa[64*PAD];
    int tx = threadIdx.x, lane = tx & 63;
    int c0 = __builtin_amdgcn_readfirstlane((tx >> 6) * 16);
    size_t row0 = (size_t)blockIdx.x * 64;
    stage64(xin  + row0*CD, 64, sx, tx);
    stage64(aggb + row0*CD, 64, sa, tx);
    __syncthreads();

    float acc[16], r[16], hn[16], z[16];

    // hn = b_hh[n] + x @ w_hh[n].T
    #pragma unroll
    for (int j = 0; j < 16; ++j) acc[j] = bhh[128 + c0 + j];
    dotpass(acc, whh + 128*64, c0, sx, lane);
    #pragma unroll
    for (int j = 0; j < 16; ++j) hn[j] = acc[j];

    // r = sigmoid(b_ih[r]+b_hh[r] + agg@w_ih[r].T + x@w_hh[r].T)
    #pragma unroll
    for (int j = 0; j < 16; ++j) acc[j] = bih[c0 + j] + bhh[c0 + j];
    dotpass(acc, wih, c0, sa, lane);
    dotpass(acc, whh, c0, sx, lane);
    #pragma unroll
    for (int j = 0; j < 16; ++j) r[j] = sigm(acc[j]);

    // n = tanh(b_ih[n] + agg@w_ih[n].T + r*hn)   (store into hn)
    #pragma unroll
    for (int j = 0; j < 16; ++j) acc[j] = bih[128 + c0 + j];
    dotpass(acc, wih + 128*64, c0, sa, lane);
    #pragma unroll
    for (int j = 0; j < 16; ++j) hn[j] = tanhf(acc[j] + r[j]*hn[j]);

    // z = sigmoid(b_ih[z]+b_hh[z] + agg@w_ih[z].T + x@w_hh[z].T)
    #pragma unroll
    for (int j = 0; j < 16; ++j) acc[j] = bih[64 + c0 + j] + bhh[64 + c0 + j];
    dotpass(acc, wih + 64*64, c0, sa, lane);
    dotpass(acc, whh + 64*64, c0, sx, lane);
    #pragma unroll
    for (int j = 0; j < 16; ++j) z[j] = sigm(acc[j]);

    // x' = (1-z)*n + z*x
    float xp[16];
    #pragma unroll
    for (int j = 0; j < 16; ++j)
        xp[j] = (1.f - z[j])*hn[j] + z[j]*sx[lane*PAD + c0 + j];

    __syncthreads();                       // all waves done reading sa (agg)
    #pragma unroll
    for (int j = 0; j < 16; ++j) sa[lane*PAD + c0 + j] = xp[j];   // sa now holds x' (node-major)
    __syncthreads();

    // coalesced dump of x'
    #pragma unroll
    for (int rr = 0; rr < 16; ++rr){
        int rw = c0 + rr;
        xout[(row0 + rw)*CD + lane] = sa[rw*PAD + lane];
    }

    if (do_m){
        float macc[16];
        #pragma unroll
        for (int j = 0; j < 16; ++j) macc[j] = 0.f;
        #pragma unroll 4
        for (int k = 0; k < 64; ++k){
            float xk = sa[lane*PAD + k];
            #pragma unroll
            for (int j = 0; j < 16; ++j) macc[j] = fmaf(Wn[k*64 + c0 + j], xk, macc[j]);
        }
        #pragma unroll
        for (int j = 0; j < 16; ++j) sx[lane*PAD + c0 + j] = macc[j];
        __syncthreads();
        #pragma unroll
        for (int rr = 0; rr < 16; ++rr){
            int rw = c0 + rr;
            mout[(row0 + rw)*CD + lane] = sx[rw*PAD + lane];
        }
    }
}

// ---------------- attention + pooling (atomic partial sums) ----------------
__global__ __launch_bounds__(256) void k_att(const float* __restrict__ x, const float* __restrict__ x0,
                                             const float* __restrict__ aiw, const float* __restrict__ aib,
                                             const float* __restrict__ ajw, const float* __restrict__ ajb,
                                             float* __restrict__ pooled){
    __shared__ float sx[64*PAD];
    __shared__ float s0[64*PAD];
    const int tilesPerB = (NN + 63)/64;   // 782
    int tx = threadIdx.x, lane = tx & 63;
    int c0 = __builtin_amdgcn_readfirstlane((tx >> 6) * 32);
    int b  = blockIdx.x / tilesPerB;
    int tb = blockIdx.x % tilesPerB;
    int n0 = tb*64;
    int nvalid = NN - n0; if (nvalid > 64) nvalid = 64;
    size_t row0 = (size_t)b*NN + n0;
    stage64(x  + row0*CD, nvalid, sx, tx);
    stage64(x0 + row0*CD, nvalid, s0, tx);
    __syncthreads();

    float ai[32], aj[32];
    #pragma unroll
    for (int j = 0; j < 32; ++j){ ai[j] = aib[c0 + j]; aj[j] = ajb[c0 + j]; }

    for (int kc = 0; kc < 8; ++kc){
        float xk[16];
        const float* src = (kc < 4) ? sx : s0;
        int ko = (kc & 3) * 16;
        #pragma unroll
        for (int t = 0; t < 16; ++t) xk[t] = src[lane*PAD + ko + t];
        int kbase = kc*16;
        #pragma unroll
        for (int j = 0; j < 32; ++j){
            #pragma unroll
            for (int t = 0; t < 16; ++t){
                ai[j] = fmaf(aiw[(c0 + j)*128 + kbase + t], xk[t], ai[j]);
                aj[j] = fmaf(ajw[(c0 + j)*128 + kbase + t], xk[t], aj[j]);
            }
        }
    }

    bool valid = (lane < nvalid);
    float outv = 0.f;
    #pragma unroll
    for (int j = 0; j < 32; ++j){
        float s  = sigm(ai[j]);
        float rl = aj[j] > 0.f ? aj[j] : 0.f;
        float v  = valid ? s*rl : 0.f;
        v += __shfl_xor(v, 1);  v += __shfl_xor(v, 2);  v += __shfl_xor(v, 4);
        v += __shfl_xor(v, 8);  v += __shfl_xor(v, 16); v += __shfl_xor(v, 32);
        if (lane == j) outv = v;
    }
    if (lane < 32) atomicAdd(&pooled[b*128 + c0 + lane], outv);
}

// ---------------- final MLP + critic ----------------
__global__ __launch_bounds__(256) void k_final(const float* __restrict__ pooled, const float* __restrict__ mw,
                                               const float* __restrict__ mb, const float* __restrict__ cw,
                                               const float* __restrict__ cb, float* __restrict__ out){
    __shared__ float red[256];
    int t = threadIdx.x;
    for (int b = 0; b < NB; ++b){
        float acc = mb[t];
        #pragma unroll 8
        for (int k = 0; k < 128; ++k){
            float p = pooled[b*128 + k];
            p = p > 0.f ? p : 0.f;
            acc = fmaf(p, mw[t*128 + k], acc);
        }
        float st = acc > 0.f ? acc : 0.f;
        red[t] = st * cw[t];
        __syncthreads();
        for (int off = 128; off > 0; off >>= 1){
            if (t < off) red[t] += red[t + off];
            __syncthreads();
        }
        if (t == 0) out[b] = red[0] + cb[0];
        __syncthreads();
    }
}

extern "C" void kernel_launch(void* const* d_in, const int* in_sizes, int n_in,
                              void* d_out, int out_size, void* d_ws, size_t ws_size,
                              hipStream_t stream) {
    const float* cov   = (const float*)d_in[0];
    const float* nodes = (const float*)d_in[1];
    const int*   edges = (const int*)d_in[2];
    const int*   c2l   = (const int*)d_in[3];
    const float* ggc   = (const float*)d_in[4];
    const float* wih   = (const float*)d_in[5];
    const float* whh   = (const float*)d_in[6];
    const float* bih   = (const float*)d_in[7];
    const float* bhh   = (const float*)d_in[8];
    const float* aiw   = (const float*)d_in[9];
    const float* aib   = (const float*)d_in[10];
    const float* ajw   = (const float*)d_in[11];
    const float* ajb   = (const float*)d_in[12];
    const float* mlpw  = (const float*)d_in[13];
    const float* mlpb  = (const float*)d_in[14];
    const float* cw    = (const float*)d_in[15];
    const float* cb    = (const float*)d_in[16];
    float* out = (float*)d_out;

    const size_t XSZ = (size_t)BN * CD;          // 12.8M floats
    float* ws = (float*)d_ws;
    float* x      = ws;
    float* x0     = ws + XSZ;
    float* mbuf   = ws + 2*XSZ;
    float* agg    = ws + 3*XSZ;
    float* pooled = ws + 4*XSZ;                  // 512 floats
    int* ib        = (int*)(pooled + 512);
    int* cnt       = ib;                          // NN
    int* tmp       = cnt + NN;                    // NN
    int* bsum      = tmp + NN;                    // 256
    int* boff      = bsum + 256;                  // 256
    int* row_start = boff + 256;                  // NN+1
    int* cursor    = row_start + (NN + 1);        // NN
    int* csr_src   = cursor + NN;                 // NE

    hipMemsetAsync(cnt, 0, (size_t)NN*sizeof(int), stream);
    hipMemsetAsync(pooled, 0, 512*sizeof(float), stream);

    k_hist<<<(NE + 255)/256, 256, 0, stream>>>(edges, cnt);
    k_scan1<<<SCAN_NBLK, 256, 0, stream>>>(cnt, tmp, bsum);
    k_scan2<<<1, 256, 0, stream>>>(bsum, boff);
    k_scan3<<<SCAN_NBLK, 256, 0, stream>>>(tmp, boff, row_start, cursor);
    k_fillcsr<<<(NE + 255)/256, 256, 0, stream>>>(edges, cursor, csr_src);

    k_x0<<<(BN*16)/256, 256, 0, stream>>>(nodes, x0);
    k_cov<<<(NB*NL + 255)/256, 256, 0, stream>>>(cov, c2l, x0);

    // layer 0 message
    k_mm64<<<NTILES, 256, 0, stream>>>(x0, ggc, mbuf);

    for (int i = 0; i < NLAY; ++i){
        k_agg<<<NN/4, 256, 0, stream>>>(mbuf, row_start, csr_src, agg);
        const float* xin = (i == 0) ? x0 : x;
        int do_m = (i < NLAY - 1);
        const float* Wn = ggc + (size_t)(i + 1)*64*64;
        k_gru<<<NTILES, 256, 0, stream>>>(xin, agg, wih, whh, bih, bhh,
                                          do_m ? Wn : ggc, x, mbuf, do_m);
    }

    k_att<<<NB*((NN + 63)/64), 256, 0, stream>>>(x, x0, aiw, aib, ajw, ajb, pooled);
    k_final<<<1, 256, 0, stream>>>(pooled, mlpw, mlpb, cw, cb, out);
    (void)in_sizes; (void)n_in; (void)out_size; (void)ws_size;
}

// Round 2
// 899.162 us; speedup vs baseline: 3.3804x; 3.3804x over previous
//
#include <hip/hip_runtime.h>
#include <math.h>

#define NN 50000
#define NF 63
#define NE 800000
#define NL 10000
#define NB 4
#define NLAY 5
#define BN (NB*NN)                 // 200000 rows
#define NTILES (BN/64)             // 3125
#define SCAN_NBLK ((NN+255)/256)   // 196
#define ATILES ((NN+63)/64)        // 782

using f32x4  = __attribute__((ext_vector_type(4))) float;
using bf16x8 = __attribute__((ext_vector_type(8))) __bf16;

__device__ __forceinline__ float sigm(float v){ return 1.f/(1.f + __expf(-v)); }

__device__ __forceinline__ ushort f2bf(float f){
    uint u = __builtin_bit_cast(uint, f);
    u += 0x7fffu + ((u >> 16) & 1u);
    return (ushort)(u >> 16);
}
__device__ __forceinline__ float bf_lo(uint v){ return __builtin_bit_cast(float, v << 16); }
__device__ __forceinline__ float bf_hi(uint v){ return __builtin_bit_cast(float, v & 0xffff0000u); }

__device__ __forceinline__ bf16x8 ldfragG(const ushort* p){
    uint4 v = *(const uint4*)p;
    return __builtin_bit_cast(bf16x8, v);
}
__device__ __forceinline__ bf16x8 ldfragL(const ushort* p){
    uint4 v = *(const uint4*)p;
    return __builtin_bit_cast(bf16x8, v);
}
__device__ __forceinline__ f32x4 MFMA(bf16x8 a, bf16x8 b, f32x4 c){
    return __builtin_amdgcn_mfma_f32_16x16x32_bf16(a, b, c, 0, 0, 0);
}

// ---------------- CSR build ----------------
__global__ void k_hist(const int* __restrict__ edges, int* __restrict__ cnt){
    int e = blockIdx.x*256 + threadIdx.x;
    if (e < NE) atomicAdd(&cnt[edges[NE + e]], 1);
}

__global__ void k_scan1(const int* __restrict__ cnt, int* __restrict__ tmp, int* __restrict__ bsum){
    __shared__ int sh[256];
    int tx = threadIdx.x, i = blockIdx.x*256 + tx;
    int v = (i < NN) ? cnt[i] : 0;
    sh[tx] = v; __syncthreads();
    for (int off = 1; off < 256; off <<= 1){
        int u = (tx >= off) ? sh[tx-off] : 0;
        __syncthreads();
        sh[tx] += u;
        __syncthreads();
    }
    int incl = sh[tx];
    if (i < NN) tmp[i] = incl - v;
    if (tx == 255) bsum[blockIdx.x] = incl;
}

__global__ void k_scan2(const int* __restrict__ bsum, int* __restrict__ boff){
    __shared__ int sh[256];
    int tx = threadIdx.x;
    int v = (tx < SCAN_NBLK) ? bsum[tx] : 0;
    sh[tx] = v; __syncthreads();
    for (int off = 1; off < 256; off <<= 1){
        int u = (tx >= off) ? sh[tx-off] : 0;
        __syncthreads();
        sh[tx] += u;
        __syncthreads();
    }
    boff[tx] = sh[tx] - v;
}

__global__ void k_scan3(const int* __restrict__ tmp, const int* __restrict__ boff,
                        int* __restrict__ row_start, int* __restrict__ cursor){
    int i = blockIdx.x*256 + threadIdx.x;
    if (i < NN){
        int rs = tmp[i] + boff[blockIdx.x];
        row_start[i] = rs;
        cursor[i] = rs;
    }
    if (i == 0) row_start[NN] = NE;
}

__global__ void k_fillcsr(const int* __restrict__ edges, int* __restrict__ cursor, int* __restrict__ csr_src){
    int e = blockIdx.x*256 + threadIdx.x;
    if (e < NE){
        int d = edges[NE + e];
        int pos = atomicAdd(&cursor[d], 1);
        csr_src[pos] = edges[e];
    }
}

// ---------------- weight prep: fp32 -> bf16 (+ transpose for ggc) ----------------
__global__ void k_prep(const float* __restrict__ wih, const float* __restrict__ whh,
                       const float* __restrict__ aiw, const float* __restrict__ ajw,
                       const float* __restrict__ ggc,
                       ushort* __restrict__ wihb, ushort* __restrict__ whhb,
                       ushort* __restrict__ aiwb, ushort* __restrict__ ajwb,
                       ushort* __restrict__ GTb){
    int i = blockIdx.x*256 + threadIdx.x;       // 0..77823
    if (i < 12288)        wihb[i]        = f2bf(wih[i]);
    else if (i < 24576)   whhb[i-12288]  = f2bf(whh[i-12288]);
    else if (i < 40960)   aiwb[i-24576]  = f2bf(aiw[i-24576]);
    else if (i < 57344)   ajwb[i-40960]  = f2bf(ajw[i-40960]);
    else {
        int t = i - 57344;                       // 0..20479
        int mi = t >> 12, rem = t & 4095;
        int n = rem >> 6, k = rem & 63;
        GTb[t] = f2bf(ggc[mi*4096 + k*64 + n]);  // GT[i][n][k] = ggc[i][k][n]
    }
}

// ---------------- x0 build ----------------
__global__ void k_x0(const float* __restrict__ nodes, float* __restrict__ x0){
    int f = blockIdx.x*256 + threadIdx.x;       // float4 index, BN*16 total
    int row = f >> 4, c4 = f & 15;
    int n = row % NN;
    float v[4];
    #pragma unroll
    for (int i = 0; i < 4; ++i){
        int c = c4*4 + i;
        v[i] = (c < NF) ? nodes[(size_t)n*NF + c] : 0.f;
    }
    ((float4*)x0)[f] = make_float4(v[0], v[1], v[2], v[3]);
}

__global__ void k_cov(const float* __restrict__ cov, const int* __restrict__ c2l, float* __restrict__ x0){
    int i = blockIdx.x*256 + threadIdx.x;
    if (i < NB*NL){
        int b = i / NL, j = i % NL;
        int nd = c2l[j];
        x0[((size_t)b*NN + nd)*64 + 63] = cov[i];
    }
}

// ---------------- layer-0 message: m = x0 @ W0  (bf16 MFMA) ----------------
__global__ __launch_bounds__(256) void k_mm0(const float* __restrict__ xin, const ushort* __restrict__ GT0,
                                             ushort* __restrict__ mout){
    __shared__ __align__(16) ushort sA[64*72];
    const int tx = threadIdx.x;
    const int l  = tx & 63, li = l & 15, q = l >> 4;
    const int w  = __builtin_amdgcn_readfirstlane(tx >> 6);
    const size_t row0 = (size_t)blockIdx.x * 64;
    const float4* x4 = (const float4*)(xin + row0*64);
    #pragma unroll
    for (int it = 0; it < 4; ++it){
        int idx = it*256 + tx;
        int r = idx >> 4, c4 = idx & 15;
        float4 v = x4[r*16 + c4];
        uint2 pk;
        pk.x = (uint)f2bf(v.x) | ((uint)f2bf(v.y) << 16);
        pk.y = (uint)f2bf(v.z) | ((uint)f2bf(v.w) << 16);
        *(uint2*)(&sA[r*72 + c4*4]) = pk;
    }
    __syncthreads();
    const int n0 = 16*w;
    f32x4 Cm[4];
    #pragma unroll
    for (int m = 0; m < 4; ++m) Cm[m] = (f32x4){0.f,0.f,0.f,0.f};
    #pragma unroll
    for (int ks = 0; ks < 2; ++ks){
        bf16x8 B = ldfragG(GT0 + (size_t)(n0 + li)*64 + ks*32 + q*8);
        #pragma unroll
        for (int m = 0; m < 4; ++m){
            bf16x8 A = ldfragL(&sA[(m*16 + li)*72 + ks*32 + q*8]);
            Cm[m] = MFMA(A, B, Cm[m]);
        }
    }
    const int c = n0 + li;
    #pragma unroll
    for (int m = 0; m < 4; ++m){
        #pragma unroll
        for (int rg = 0; rg < 4; ++rg){
            int rl = m*16 + q*4 + rg;
            size_t rowg = row0 + rl;
            int nidx = (int)(rowg % NN), b = (int)(rowg / NN);
            mout[((size_t)nidx*NB + b)*64 + c] = f2bf(Cm[m][rg]);
        }
    }
}

// ---------------- agg: gather-sum of bf16 messages ----------------
__global__ __launch_bounds__(256) void k_agg(const ushort* __restrict__ m,
                                             const int* __restrict__ row_start,
                                             const int* __restrict__ csr_src,
                                             ushort* __restrict__ agg){
    int tx = threadIdx.x, l = tx & 63, w = tx >> 6;
    int d = __builtin_amdgcn_readfirstlane(blockIdx.x*2 + (w >> 1));
    int b = (w & 1)*2 + (l >> 5);
    int c2 = l & 31;
    int e0 = row_start[d], e1 = row_start[d+1];
    float a0 = 0.f, a1 = 0.f;
    const uint voff = (uint)(b*64 + c2*2);
    int e = e0;
    for (; e + 1 < e1; e += 2){
        int s0 = csr_src[e], s1 = csr_src[e+1];
        uint v0 = *(const uint*)(m + (size_t)s0*256 + voff);
        uint v1 = *(const uint*)(m + (size_t)s1*256 + voff);
        a0 += bf_lo(v0) + bf_lo(v1);
        a1 += bf_hi(v0) + bf_hi(v1);
    }
    if (e < e1){
        int s0 = csr_src[e];
        uint v0 = *(const uint*)(m + (size_t)s0*256 + voff);
        a0 += bf_lo(v0);
        a1 += bf_hi(v0);
    }
    uint o = (uint)f2bf(a0) | ((uint)f2bf(a1) << 16);
    *(uint*)(agg + ((size_t)b*NN + d)*64 + c2*2) = o;
}

// ---------------- fused GRU (MFMA) + next-layer message ----------------
__global__ __launch_bounds__(256) void k_gru(const float* __restrict__ xin, const ushort* __restrict__ aggb,
                                             const ushort* __restrict__ wihb, const ushort* __restrict__ whhb,
                                             const float* __restrict__ bih, const float* __restrict__ bhh,
                                             const ushort* __restrict__ GTn, float* __restrict__ xout,
                                             ushort* __restrict__ mout, int do_m){
    __shared__ __align__(16) ushort sA[64*136];   // [agg | x] bf16, stride 136
    __shared__ float sxf[64*65];                  // x fp32
    const int tx = threadIdx.x;
    const int l  = tx & 63, li = l & 15, q = l >> 4;
    const int w  = __builtin_amdgcn_readfirstlane(tx >> 6);
    const size_t row0 = (size_t)blockIdx.x * 64;

    #pragma unroll
    for (int it = 0; it < 2; ++it){
        int idx = it*256 + tx;                    // 0..511
        int r = idx >> 3, g = idx & 7;
        uint4 v = *(const uint4*)(aggb + (row0 + r)*64 + g*8);
        *(uint4*)(&sA[r*136 + g*8]) = v;
    }
    const float4* x4 = (const float4*)(xin + row0*64);
    #pragma unroll
    for (int it = 0; it < 4; ++it){
        int idx = it*256 + tx;                    // 0..1023
        int r = idx >> 4, c4 = idx & 15;
        float4 v = x4[r*16 + c4];
        int fb = r*65 + c4*4;
        sxf[fb+0]=v.x; sxf[fb+1]=v.y; sxf[fb+2]=v.z; sxf[fb+3]=v.w;
        uint2 pk;
        pk.x = (uint)f2bf(v.x) | ((uint)f2bf(v.y) << 16);
        pk.y = (uint)f2bf(v.z) | ((uint)f2bf(v.w) << 16);
        *(uint2*)(&sA[r*136 + 64 + c4*4]) = pk;
    }
    __syncthreads();

    const int n0 = 16*w;
    f32x4 Cr[4], Cz[4], Cxn[4], Chn[4];
    #pragma unroll
    for (int m = 0; m < 4; ++m){
        Cr[m]=(f32x4){0.f,0.f,0.f,0.f}; Cz[m]=(f32x4){0.f,0.f,0.f,0.f};
        Cxn[m]=(f32x4){0.f,0.f,0.f,0.f}; Chn[m]=(f32x4){0.f,0.f,0.f,0.f};
    }
    bf16x8 Bxn[2], Bhn[2];
    #pragma unroll
    for (int ks = 0; ks < 2; ++ks){
        Bxn[ks] = ldfragG(wihb + (size_t)(128 + n0 + li)*64 + ks*32 + q*8);
        Bhn[ks] = ldfragG(whhb + (size_t)(128 + n0 + li)*64 + ks*32 + q*8);
    }
    #pragma unroll
    for (int ks = 0; ks < 4; ++ks){
        const ushort* wb = (ks < 2) ? wihb : whhb;
        int kb = (ks & 1)*32;
        bf16x8 Br = ldfragG(wb + (size_t)(n0 + li)*64 + kb + q*8);
        bf16x8 Bz = ldfragG(wb + (size_t)(64 + n0 + li)*64 + kb + q*8);
        #pragma unroll
        for (int m = 0; m < 4; ++m){
            bf16x8 A = ldfragL(&sA[(m*16 + li)*136 + ks*32 + q*8]);
            Cr[m] = MFMA(A, Br, Cr[m]);
            Cz[m] = MFMA(A, Bz, Cz[m]);
            if (ks < 2) Cxn[m] = MFMA(A, Bxn[ks], Cxn[m]);
            else        Chn[m] = MFMA(A, Bhn[ks-2], Chn[m]);
        }
    }

    const int c = n0 + li;
    const float br_ = bih[c]     + bhh[c];
    const float bz_ = bih[64+c]  + bhh[64+c];
    const float bn_ = bih[128+c];
    const float bh_ = bhh[128+c];
    float xnew[4][4];
    #pragma unroll
    for (int m = 0; m < 4; ++m){
        #pragma unroll
        for (int rg = 0; rg < 4; ++rg){
            int rl = m*16 + q*4 + rg;
            float r = sigm(Cr[m][rg] + br_);
            float z = sigm(Cz[m][rg] + bz_);
            float n = tanhf(Cxn[m][rg] + bn_ + r*(Chn[m][rg] + bh_));
            float xo = sxf[rl*65 + c];
            float v = (1.f - z)*n + z*xo;
            xnew[m][rg] = v;
            xout[(row0 + rl)*64 + c] = v;
        }
    }
    __syncthreads();
    #pragma unroll
    for (int m = 0; m < 4; ++m){
        #pragma unroll
        for (int rg = 0; rg < 4; ++rg){
            int rl = m*16 + q*4 + rg;
            sA[rl*136 + 64 + c] = f2bf(xnew[m][rg]);
        }
    }
    __syncthreads();
    if (do_m){
        f32x4 Cm[4];
        #pragma unroll
        for (int m = 0; m < 4; ++m) Cm[m] = (f32x4){0.f,0.f,0.f,0.f};
        #pragma unroll
        for (int ks = 0; ks < 2; ++ks){
            bf16x8 B = ldfragG(GTn + (size_t)(n0 + li)*64 + ks*32 + q*8);
            #pragma unroll
            for (int m = 0; m < 4; ++m){
                bf16x8 A = ldfragL(&sA[(m*16 + li)*136 + 64 + ks*32 + q*8]);
                Cm[m] = MFMA(A, B, Cm[m]);
            }
        }
        #pragma unroll
        for (int m = 0; m < 4; ++m){
            #pragma unroll
            for (int rg = 0; rg < 4; ++rg){
                int rl = m*16 + q*4 + rg;
                size_t rowg = row0 + rl;
                int nidx = (int)(rowg % NN), b = (int)(rowg / NN);
                mout[((size_t)nidx*NB + b)*64 + c] = f2bf(Cm[m][rg]);
            }
        }
    }
}

// ---------------- attention + pooling (MFMA) ----------------
__global__ __launch_bounds__(256) void k_att(const float* __restrict__ x, const float* __restrict__ x0,
                                             const ushort* __restrict__ aiwb, const float* __restrict__ aib,
                                             const ushort* __restrict__ ajwb, const float* __restrict__ ajb,
                                             float* __restrict__ pooled){
    __shared__ __align__(16) ushort sC[64*136];   // [x | x0] bf16
    const int tx = threadIdx.x;
    const int l  = tx & 63, li = l & 15, q = l >> 4;
    const int w  = __builtin_amdgcn_readfirstlane(tx >> 6);
    const int b  = blockIdx.x / ATILES;
    const int tb = blockIdx.x % ATILES;
    const int nrow0 = tb*64;
    int nvalid = NN - nrow0; if (nvalid > 64) nvalid = 64;
    const size_t row0 = (size_t)b*NN + nrow0;
    const float4* xa = (const float4*)(x  + row0*64);
    const float4* x0a = (const float4*)(x0 + row0*64);
    #pragma unroll
    for (int it = 0; it < 4; ++it){
        int idx = it*256 + tx;
        int r = idx >> 4, c4 = idx & 15;
        float4 vx = make_float4(0.f,0.f,0.f,0.f), v0 = vx;
        if (r < nvalid){ vx = xa[r*16 + c4]; v0 = x0a[r*16 + c4]; }
        uint2 pk;
        pk.x = (uint)f2bf(vx.x) | ((uint)f2bf(vx.y) << 16);
        pk.y = (uint)f2bf(vx.z) | ((uint)f2bf(vx.w) << 16);
        *(uint2*)(&sC[r*136 + c4*4]) = pk;
        pk.x = (uint)f2bf(v0.x) | ((uint)f2bf(v0.y) << 16);
        pk.y = (uint)f2bf(v0.z) | ((uint)f2bf(v0.w) << 16);
        *(uint2*)(&sC[r*136 + 64 + c4*4]) = pk;
    }
    __syncthreads();

    const int nb0 = 32*w;
    f32x4 Ai[2][4], Aj[2][4];
    #pragma unroll
    for (int t = 0; t < 2; ++t)
        #pragma unroll
        for (int m = 0; m < 4; ++m){ Ai[t][m]=(f32x4){0.f,0.f,0.f,0.f}; Aj[t][m]=(f32x4){0.f,0.f,0.f,0.f}; }

    #pragma unroll
    for (int ks = 0; ks < 4; ++ks){
        bf16x8 Bi[2], Bj[2];
        #pragma unroll
        for (int t = 0; t < 2; ++t){
            Bi[t] = ldfragG(aiwb + (size_t)(nb0 + 16*t + li)*128 + ks*32 + q*8);
            Bj[t] = ldfragG(ajwb + (size_t)(nb0 + 16*t + li)*128 + ks*32 + q*8);
        }
        #pragma unroll
        for (int m = 0; m < 4; ++m){
            bf16x8 A = ldfragL(&sC[(m*16 + li)*136 + ks*32 + q*8]);
            #pragma unroll
            for (int t = 0; t < 2; ++t){
                Ai[t][m] = MFMA(A, Bi[t], Ai[t][m]);
                Aj[t][m] = MFMA(A, Bj[t], Aj[t][m]);
            }
        }
    }

    #pragma unroll
    for (int t = 0; t < 2; ++t){
        int c = nb0 + 16*t + li;
        float bia = aib[c], bja = ajb[c];
        float vs = 0.f;
        #pragma unroll
        for (int m = 0; m < 4; ++m){
            #pragma unroll
            for (int rg = 0; rg < 4; ++rg){
                int rl = m*16 + q*4 + rg;
                if (rl < nvalid){
                    float s = sigm(Ai[t][m][rg] + bia);
                    float a = Aj[t][m][rg] + bja;
                    a = a > 0.f ? a : 0.f;
                    vs += s*a;
                }
            }
        }
        vs += __shfl_xor(vs, 16);
        vs += __shfl_xor(vs, 32);
        if (l < 16) atomicAdd(&pooled[b*128 + nb0 + 16*t + l], vs);
    }
}

// ---------------- final MLP + critic ----------------
__global__ __launch_bounds__(256) void k_final(const float* __restrict__ pooled, const float* __restrict__ mw,
                                               const float* __restrict__ mb, const float* __restrict__ cw,
                                               const float* __restrict__ cb, float* __restrict__ out){
    __shared__ float red[256];
    int t = threadIdx.x;
    for (int b = 0; b < NB; ++b){
        float acc = mb[t];
        #pragma unroll 8
        for (int k = 0; k < 128; ++k){
            float p = pooled[b*128 + k];
            p = p > 0.f ? p : 0.f;
            acc = fmaf(p, mw[t*128 + k], acc);
        }
        float st = acc > 0.f ? acc : 0.f;
        red[t] = st * cw[t];
        __syncthreads();
        for (int off = 128; off > 0; off >>= 1){
            if (t < off) red[t] += red[t + off];
            __syncthreads();
        }
        if (t == 0) out[b] = red[0] + cb[0];
        __syncthreads();
    }
}

extern "C" void kernel_launch(void* const* d_in, const int* in_sizes, int n_in,
                              void* d_out, int out_size, void* d_ws, size_t ws_size,
                              hipStream_t stream) {
    const float* cov   = (const float*)d_in[0];
    const float* nodes = (const float*)d_in[1];
    const int*   edges = (const int*)d_in[2];
    const int*   c2l   = (const int*)d_in[3];
    const float* ggc   = (const float*)d_in[4];
    const float* wih   = (const float*)d_in[5];
    const float* whh   = (const float*)d_in[6];
    const float* bih   = (const float*)d_in[7];
    const float* bhh   = (const float*)d_in[8];
    const float* aiw   = (const float*)d_in[9];
    const float* aib   = (const float*)d_in[10];
    const float* ajw   = (const float*)d_in[11];
    const float* ajb   = (const float*)d_in[12];
    const float* mlpw  = (const float*)d_in[13];
    const float* mlpb  = (const float*)d_in[14];
    const float* cw    = (const float*)d_in[15];
    const float* cb    = (const float*)d_in[16];
    float* out = (float*)d_out;

    const size_t XSZ = (size_t)BN * 64;          // 12.8M
    float* ws = (float*)d_ws;
    float* x      = ws;
    float* x0     = ws + XSZ;
    float* pooled = ws + 2*XSZ;                  // 512 floats
    ushort* mB    = (ushort*)(pooled + 512);     // BN*64 bf16, interleaved [n][b][64]
    ushort* aggB  = mB + XSZ;                    // BN*64 bf16, [b*NN+n][64]
    ushort* wihb  = aggB + XSZ;                  // 12288
    ushort* whhb  = wihb + 12288;                // 12288
    ushort* aiwb  = whhb + 12288;                // 16384
    ushort* ajwb  = aiwb + 16384;                // 16384
    ushort* GTb   = ajwb + 16384;                // 20480
    int* cnt       = (int*)(GTb + 20480);
    int* tmp       = cnt + NN;
    int* bsum      = tmp + NN;
    int* boff      = bsum + 256;
    int* row_start = boff + 256;
    int* cursor    = row_start + (NN + 1);
    int* csr_src   = cursor + NN;

    hipMemsetAsync(cnt, 0, (size_t)NN*sizeof(int), stream);
    hipMemsetAsync(pooled, 0, 512*sizeof(float), stream);

    k_prep<<<304, 256, 0, stream>>>(wih, whh, aiw, ajw, ggc, wihb, whhb, aiwb, ajwb, GTb);

    k_hist<<<(NE + 255)/256, 256, 0, stream>>>(edges, cnt);
    k_scan1<<<SCAN_NBLK, 256, 0, stream>>>(cnt, tmp, bsum);
    k_scan2<<<1, 256, 0, stream>>>(bsum, boff);
    k_scan3<<<SCAN_NBLK, 256, 0, stream>>>(tmp, boff, row_start, cursor);
    k_fillcsr<<<(NE + 255)/256, 256, 0, stream>>>(edges, cursor, csr_src);

    k_x0<<<(BN*16)/256, 256, 0, stream>>>(nodes, x0);
    k_cov<<<(NB*NL + 255)/256, 256, 0, stream>>>(cov, c2l, x0);

    k_mm0<<<NTILES, 256, 0, stream>>>(x0, GTb, mB);

    for (int i = 0; i < NLAY; ++i){
        k_agg<<<NN/2, 256, 0, stream>>>(mB, row_start, csr_src, aggB);
        const float* xin = (i == 0) ? x0 : x;
        int do_m = (i < NLAY - 1);
        const ushort* GTn = GTb + (size_t)(do_m ? (i + 1) : 0)*4096;
        k_gru<<<NTILES, 256, 0, stream>>>(xin, aggB, wihb, whhb, bih, bhh,
                                          GTn, x, mB, do_m);
    }

    k_att<<<NB*ATILES, 256, 0, stream>>>(x, x0, aiwb, aib, ajwb, ajb, pooled);
    k_final<<<1, 256, 0, stream>>>(pooled, mlpw, mlpb, cw, cb, out);
    (void)in_sizes; (void)n_in; (void)out_size; (void)ws_size;
}